// Round 6
// baseline (153.702 us; speedup 1.0000x reference)
//
#include <hip/hip_runtime.h>
#include <hip/hip_bf16.h>

typedef __attribute__((ext_vector_type(8))) short short8;
typedef __attribute__((ext_vector_type(4))) float f32x4;

#define MFMA16(a,b,c) __builtin_amdgcn_mfma_f32_16x16x32_bf16((a),(b),(c),0,0,0)

static __device__ __forceinline__ unsigned int f2bf(float f){
    unsigned int u = __float_as_uint(f);
    u += 0x7FFFu + ((u >> 16) & 1u);
    return u >> 16;
}

static __device__ __forceinline__ short8 pack8(float4 a, float4 b){
    short8 r;
    r[0]=(short)f2bf(a.x); r[1]=(short)f2bf(a.y);
    r[2]=(short)f2bf(a.z); r[3]=(short)f2bf(a.w);
    r[4]=(short)f2bf(b.x); r[5]=(short)f2bf(b.y);
    r[6]=(short)f2bf(b.z); r[7]=(short)f2bf(b.w);
    return r;
}

// ---- mask dtype sniffer: int32 bools are all in {0,1}; byte-bools packed
// into int words set bytes 1..3 somewhere in the first 4096 words.
__global__ void detect_mask_k(const int* __restrict__ m, int* __restrict__ flag){
    __shared__ int any_hi;
    if (threadIdx.x == 0) any_hi = 0;
    __syncthreads();
    int acc = 0;
    #pragma unroll
    for (int it = 0; it < 16; ++it)
        acc |= m[it*256 + threadIdx.x];
    if (acc & 0xFFFFFF00) atomicOr(&any_hi, 1);
    __syncthreads();
    if (threadIdx.x == 0) *flag = any_hi;   // 1 = byte layout, 0 = int32 layout
}

// ---- mask -> bit-packed [b][q][32 words] (1 bit per key, 1 = masked/-inf)
__global__ __launch_bounds__(256) void mask_prep_k(
    const unsigned int* __restrict__ m, const int* __restrict__ flag,
    unsigned int* __restrict__ bmout)
{
    const int tid  = threadIdx.x;
    const int lane = tid & 63;
    const unsigned int gbase = blockIdx.x*256u + tid;
    if (*flag == 0){
        for (int it = 0; it < 32; ++it){
            unsigned int idx = it*262144u + gbase;
            unsigned int v = m[idx];
            unsigned long long bal = __ballot(v != 0u);
            if (lane == 0)
                *(unsigned long long*)(bmout + (idx >> 5)) = bal;
        }
    } else {
        for (int it = 0; it < 8; ++it){
            unsigned int idx = it*262144u + gbase;
            unsigned int v = m[idx];
            unsigned int nib = (v | (v>>7) | (v>>14) | (v>>21)) & 0xFu;
            unsigned int x = nib << ((lane & 7)*4);
            x |= (unsigned int)__shfl_xor((int)x, 1);
            x |= (unsigned int)__shfl_xor((int)x, 2);
            x |= (unsigned int)__shfl_xor((int)x, 4);
            if ((lane & 7) == 0)
                bmout[idx >> 3] = x;
        }
    }
}

// ---------------- QKV projection (3-way split grid) ----------------
__global__ __launch_bounds__(256) void qkv_proj_k(
    const float* __restrict__ nd,
    const float* __restrict__ Wqp, const float* __restrict__ bqp,
    const float* __restrict__ Wkp, const float* __restrict__ bkp,
    const float* __restrict__ Wvp, const float* __restrict__ bvp,
    unsigned short* __restrict__ qout, unsigned short* __restrict__ kout,
    unsigned short* __restrict__ vtout)
{
    __shared__ __align__(16) unsigned short xl[64*264];
    const int tid  = threadIdx.x;
    const int bi   = blockIdx.x;          // 384 = 3 kinds x 128 tiles
    const int kind = bi >> 7;
    const int R0   = (bi & 127) * 64;
    const int b    = R0 >> 10;
    const int n0   = R0 & 1023;

    #pragma unroll
    for (int it = 0; it < 16; ++it){
        int f4 = it*256 + tid;
        int r = f4 >> 6, c4 = f4 & 63;
        float4 v = *(const float4*)(nd + (size_t)(R0+r)*256 + c4*4);
        unsigned int lo = f2bf(v.x) | (f2bf(v.y) << 16);
        unsigned int hi = f2bf(v.z) | (f2bf(v.w) << 16);
        *(uint2*)&xl[r*264 + c4*4] = make_uint2(lo, hi);
    }
    __syncthreads();

    const int lane = tid & 63;
    const int w  = tid >> 6;
    const int ln = lane & 15;
    const int g  = lane >> 4;
    const int ow = w * 64;

    f32x4 acc[4][4];
    #pragma unroll
    for (int a=0;a<4;++a){
        #pragma unroll
        for (int c=0;c<4;++c) acc[a][c] = (f32x4){0.f,0.f,0.f,0.f};
    }

    if (kind < 2){
        const float* W  = kind ? Wkp : Wqp;
        const float* bb = kind ? bkp : bqp;
        unsigned short* op = kind ? kout : qout;
        const float scl = kind ? 1.0f : 0.17677669529663687f;
        for (int kk = 0; kk < 8; ++kk){
            short8 wf[4], xf[4];
            #pragma unroll
            for (int ot=0; ot<4; ++ot){
                const float* wp = W + (size_t)(ow + ot*16 + ln)*256 + kk*32 + g*8;
                wf[ot] = pack8(*(const float4*)wp, *(const float4*)(wp+4));
            }
            #pragma unroll
            for (int nt=0; nt<4; ++nt)
                xf[nt] = *(const short8*)&xl[(nt*16+ln)*264 + kk*32 + g*8];
            #pragma unroll
            for (int ot=0; ot<4; ++ot){
                #pragma unroll
                for (int nt=0; nt<4; ++nt)
                    acc[ot][nt] = MFMA16(wf[ot], xf[nt], acc[ot][nt]);
            }
        }
        #pragma unroll
        for (int ot=0; ot<4; ++ot){
            int o0 = ow + ot*16 + g*4;
            int h = o0 >> 5, d0 = o0 & 31;
            float4 b4 = *(const float4*)(bb + o0);
            #pragma unroll
            for (int nt=0; nt<4; ++nt){
                int n = n0 + nt*16 + ln;
                unsigned int lo = f2bf((acc[ot][nt][0]+b4.x)*scl) | (f2bf((acc[ot][nt][1]+b4.y)*scl)<<16);
                unsigned int hi = f2bf((acc[ot][nt][2]+b4.z)*scl) | (f2bf((acc[ot][nt][3]+b4.w)*scl)<<16);
                *(uint2*)(op + ((size_t)(b*8+h)*1024 + n)*32 + d0) = make_uint2(lo,hi);
            }
        }
    } else {
        for (int kk = 0; kk < 8; ++kk){
            short8 wf[4], xf[4];
            #pragma unroll
            for (int ot=0; ot<4; ++ot){
                const float* wp = Wvp + (size_t)(ow + ot*16 + ln)*256 + kk*32 + g*8;
                wf[ot] = pack8(*(const float4*)wp, *(const float4*)(wp+4));
            }
            #pragma unroll
            for (int nt=0; nt<4; ++nt)
                xf[nt] = *(const short8*)&xl[(nt*16+ln)*264 + kk*32 + g*8];
            #pragma unroll
            for (int nt=0; nt<4; ++nt){
                #pragma unroll
                for (int ot=0; ot<4; ++ot)
                    acc[nt][ot] = MFMA16(xf[nt], wf[ot], acc[nt][ot]);
            }
        }
        #pragma unroll
        for (int nt=0; nt<4; ++nt){
            int nb = n0 + nt*16 + g*4;
            #pragma unroll
            for (int ot=0; ot<4; ++ot){
                int o = ow + ot*16 + ln;
                int h = o >> 5, d = o & 31;
                float bvv = bvp[o];
                unsigned int lo = f2bf(acc[nt][ot][0]+bvv) | (f2bf(acc[nt][ot][1]+bvv)<<16);
                unsigned int hi = f2bf(acc[nt][ot][2]+bvv) | (f2bf(acc[nt][ot][3]+bvv)<<16);
                *(uint2*)(vtout + ((size_t)(b*8+h)*32 + d)*1024 + nb) = make_uint2(lo,hi);
            }
        }
    }
}

// ---------------- Fused biased-masked attention ----------------
// Block = (b, 16 q rows), 512 threads = 8 waves, 1 head/wave.
// Double-buffered LDS bias + no-drain fused-asm barrier + 2-chunk-deep
// register prefetch. BUGFIX r6 (r4/r5 fail): ATTN_LOAD(A, c+2) clobbers
// k0A..v1A/bmA BEFORE the attn_chunk call site captures them — must
// snapshot current-chunk K/V/mask into locals BEFORE issuing the reload
// (r3 did this; r4 dropped it). Bias regs are safe (staged before reload).
struct AttnState { f32x4 acc0, acc1; float m, l; };

static __device__ __forceinline__ void attn_chunk(
    AttnState& st, short8 k0, short8 k1, short8 v0, short8 v1,
    unsigned int bmc, const float* __restrict__ bsb, short8 qf,
    int w, int ln, int g)
{
    const f32x4 z4 = {0.f,0.f,0.f,0.f};
    f32x4 s0 = MFMA16(k0, qf, z4);   // S^T: col=q=ln, row=key=4g+r (keys 0..15)
    f32x4 s1 = MFMA16(k1, qf, z4);   // keys 16..31
    float pv[8];
    float mx = -1e30f;
    #pragma unroll
    for (int t=0; t<2; ++t){
        #pragma unroll
        for (int r=0; r<4; ++r){
            int keyl = t*16 + g*4 + r;
            int bidx = (t*128 + r*32 + w*4 + g)*16 + (ln ^ ((t*8 + r*2 + (w>>2)) & 15));
            float sv = (t ? s1[r] : s0[r]) + bsb[bidx];
            sv = ((bmc >> keyl) & 1u) ? -1e30f : sv;
            pv[t*4+r] = sv;
            mx = fmaxf(mx, sv);
        }
    }
    mx = fmaxf(mx, __shfl_xor(mx, 16));
    mx = fmaxf(mx, __shfl_xor(mx, 32));
    float mn = fmaxf(st.m, mx);
    float alpha = __expf(st.m - mn);
    st.m = mn;
    float ps = 0.f;
    #pragma unroll
    for (int i=0;i<8;++i){ pv[i] = __expf(pv[i]-mn); ps += pv[i]; }
    ps += __shfl_xor(ps, 16);
    ps += __shfl_xor(ps, 32);
    st.l = st.l*alpha + ps;
    #pragma unroll
    for (int r=0;r<4;++r){ st.acc0[r]*=alpha; st.acc1[r]*=alpha; }

    // redistribute P^T into B-frag layout: pack bf16 pairs, then 8 shuffles
    unsigned int A01 = f2bf(pv[0]) | (f2bf(pv[1])<<16);
    unsigned int A23 = f2bf(pv[2]) | (f2bf(pv[3])<<16);
    unsigned int B01 = f2bf(pv[4]) | (f2bf(pv[5])<<16);
    unsigned int B23 = f2bf(pv[6]) | (f2bf(pv[7])<<16);
    int s0l = (2*(g&1))*16 + ln;
    int s1l = s0l + 16;
    unsigned int a01  = (unsigned int)__shfl((int)A01, s0l);
    unsigned int a23  = (unsigned int)__shfl((int)A23, s0l);
    unsigned int b01  = (unsigned int)__shfl((int)B01, s0l);
    unsigned int b23  = (unsigned int)__shfl((int)B23, s0l);
    unsigned int a01b = (unsigned int)__shfl((int)A01, s1l);
    unsigned int a23b = (unsigned int)__shfl((int)A23, s1l);
    unsigned int b01b = (unsigned int)__shfl((int)B01, s1l);
    unsigned int b23b = (unsigned int)__shfl((int)B23, s1l);
    bool hi = (g >= 2);
    int4 pw = make_int4((int)(hi ? b01  : a01 ), (int)(hi ? b23  : a23 ),
                        (int)(hi ? b01b : a01b), (int)(hi ? b23b : a23b));
    short8 pf = *(short8*)&pw;

    st.acc0 = MFMA16(v0, pf, st.acc0);   // O^T rows d 0..15
    st.acc1 = MFMA16(v1, pf, st.acc1);   // O^T rows d 16..31
}

#define ATTN_LOAD(S, cc) do { int c1_ = (cc); \
    ba##S = *(const float4*)(bp0 + (size_t)c1_*256); \
    bb##S = *(const float4*)(bp0 + (size_t)c1_*256 + 8192); \
    k0##S = *(const short8*)(kp + c1_*1024); \
    k1##S = *(const short8*)(kp + c1_*1024 + 512); \
    v0##S = *(const short8*)(vp + c1_*32); \
    v1##S = *(const short8*)(vp + c1_*32 + 16*1024); \
    bm##S = bmp[c1_]; } while(0)

#define ATTN_STAGE(S, BUF) do { float* bsb_ = bs + (BUF)*4096; \
    bsb_[base0       + qxa] = ba##S.x;  bsb_[base0 +  64 + qxa] = ba##S.y; \
    bsb_[base0 + 128 + qxa] = ba##S.z;  bsb_[base0 + 192 + qxa] = ba##S.w; \
    bsb_[base0       + qxb] = bb##S.x;  bsb_[base0 +  64 + qxb] = bb##S.y; \
    bsb_[base0 + 128 + qxb] = bb##S.z;  bsb_[base0 + 192 + qxb] = bb##S.w; } while(0)

// snapshot current-chunk compute inputs BEFORE the prefetch reload clobbers S
#define ATTN_SNAP(S) do { \
    ck0 = k0##S; ck1 = k1##S; cv0 = v0##S; cv1 = v1##S; cbm = bm##S; } while(0)

// waitcnt + s_barrier fused in ONE asm: no schedulable gap, memory-clobbered
// on both sides; vmcnt deliberately NOT drained (prefetch stays in flight).
#define BARRIER_NODRAIN() \
    asm volatile("s_waitcnt lgkmcnt(0)\n\ts_barrier" ::: "memory")

__global__ __launch_bounds__(512, 4) void attn_k(
    const unsigned short* __restrict__ qbuf, const unsigned short* __restrict__ kbuf,
    const unsigned short* __restrict__ vtbuf, const float* __restrict__ bias,
    const unsigned int* __restrict__ bm, unsigned short* __restrict__ ab)
{
    __shared__ float bs[8192];   // 2 x 16KB double buffer
    const int tid  = threadIdx.x;
    const int bi   = blockIdx.x;        // 512 = 8 b * 64 q-tiles
    const int b    = bi >> 6;
    const int q0   = (bi & 63) * 16;
    const int lane = tid & 63;
    const int w    = tid >> 6;          // wave = head
    const int ln   = lane & 15;
    const int g    = lane >> 4;

    // Q fragment (B-operand): col=q=ln, k=d=g*8..
    const short8 qf = *(const short8*)(qbuf + ((size_t)(b*8+w)*1024 + q0 + ln)*32 + g*8);

    // staging decode: thread stages granule `lane` of rows q=2w, 2w+1
    const int h2s  = lane & 1;
    const int keys = lane >> 1;
    const int ts   = keys >> 4;
    const int rs   = keys & 3;
    const int gs   = (keys >> 2) & 3;
    const int base0 = (128*ts + 32*rs + 16*h2s + gs) * 16;
    const int xrs   = (8*ts + 2*rs + h2s) & 15;
    const int qxa   = (2*w)     ^ xrs;
    const int qxb   = (2*w + 1) ^ xrs;

    const float* bp0 = bias + ((size_t)(b*1024 + q0 + 2*w)*1024)*8 + lane*4;
    const unsigned short* kp = kbuf  + ((size_t)(b*8+w)*1024 + ln)*32 + g*8;
    const unsigned short* vp = vtbuf + ((size_t)(b*8+w)*32   + ln)*1024 + g*8;
    const unsigned int*  bmp = bm + (size_t)(b*1024 + q0 + ln)*32;

    AttnState st;
    st.acc0 = (f32x4){0.f,0.f,0.f,0.f};
    st.acc1 = (f32x4){0.f,0.f,0.f,0.f};
    st.m = -1e30f; st.l = 0.f;

    // two named prefetch register sets + current-chunk snapshots (rule #20)
    float4 baA, bbA, baB, bbB;
    short8 k0A, k1A, v0A, v1A, k0B, k1B, v0B, v1B;
    unsigned int bmA, bmB;
    short8 ck0, ck1, cv0, cv1;
    unsigned int cbm;

    ATTN_LOAD(A, 0);
    ATTN_LOAD(B, 1);
    bmA &= ~1u;                         // col 0 force-unmasked (chunk 0 only)

    for (int c = 0; c < 32; c += 2){
        // ---- phase A: stage chunk c, snapshot, prefetch c+2, compute c ----
        ATTN_STAGE(A, 0);               // consumes baA/bbA (chunk c)
        ATTN_SNAP(A);                   // capture K/V/mask of chunk c
        if (c + 2 < 32) ATTN_LOAD(A, c + 2);   // clobbers A set (ok now)
        BARRIER_NODRAIN();              // prefetch stays in flight
        attn_chunk(st, ck0, ck1, cv0, cv1, cbm, bs,        qf, w, ln, g);
        // ---- phase B: same for chunk c+1 ----
        ATTN_STAGE(B, 1);
        ATTN_SNAP(B);
        if (c + 3 < 32) ATTN_LOAD(B, c + 3);
        BARRIER_NODRAIN();
        attn_chunk(st, ck0, ck1, cv0, cv1, cbm, bs + 4096, qf, w, ln, g);
    }

    float inv = 1.0f / st.l;
    {
        int n = q0 + ln;
        unsigned int lo0 = f2bf(st.acc0[0]*inv) | (f2bf(st.acc0[1]*inv)<<16);
        unsigned int hi0 = f2bf(st.acc0[2]*inv) | (f2bf(st.acc0[3]*inv)<<16);
        *(uint2*)(ab + ((size_t)(b*1024 + n))*256 + w*32 + g*4) = make_uint2(lo0,hi0);
        unsigned int lo1 = f2bf(st.acc1[0]*inv) | (f2bf(st.acc1[1]*inv)<<16);
        unsigned int hi1 = f2bf(st.acc1[2]*inv) | (f2bf(st.acc1[3]*inv)<<16);
        *(uint2*)(ab + ((size_t)(b*1024 + n))*256 + w*32 + 16 + g*4) = make_uint2(lo1,hi1);
    }
}

// ---------------- Output projection (32-row tiles) ----------------
__global__ __launch_bounds__(256) void oproj_k(
    const unsigned short* __restrict__ ab, const float* __restrict__ Wop,
    const float* __restrict__ bop, float* __restrict__ out)
{
    __shared__ __align__(16) unsigned short al[32*264];
    const int tid = threadIdx.x;
    const int R0 = blockIdx.x * 32;   // 256 blocks
    #pragma unroll
    for (int it=0; it<4; ++it){
        int f8 = it*256 + tid;
        int r = f8 >> 5, c8 = f8 & 31;
        *(short8*)&al[r*264 + c8*8] = *(const short8*)(ab + (size_t)(R0+r)*256 + c8*8);
    }
    __syncthreads();
    const int lane = tid & 63;
    const int w = tid >> 6, ln = lane & 15, g = lane >> 4;
    const int ow = w*64;
    f32x4 acc[4][2];
    #pragma unroll
    for (int a=0;a<4;++a){ acc[a][0]=(f32x4){0.f,0.f,0.f,0.f}; acc[a][1]=(f32x4){0.f,0.f,0.f,0.f}; }
    for (int kk=0;kk<8;++kk){
        short8 wf[4], xf[2];
        #pragma unroll
        for (int ot=0;ot<4;++ot){
            const float* wp = Wop + (size_t)(ow+ot*16+ln)*256 + kk*32 + g*8;
            wf[ot] = pack8(*(const float4*)wp, *(const float4*)(wp+4));
        }
        #pragma unroll
        for (int nt=0;nt<2;++nt)
            xf[nt] = *(const short8*)&al[(nt*16+ln)*264 + kk*32 + g*8];
        #pragma unroll
        for (int ot=0;ot<4;++ot){
            #pragma unroll
            for (int nt=0;nt<2;++nt)
                acc[ot][nt] = MFMA16(wf[ot], xf[nt], acc[ot][nt]);
        }
    }
    #pragma unroll
    for (int ot=0;ot<4;++ot){
        int o0 = ow + ot*16 + g*4;
        float4 b4 = *(const float4*)(bop + o0);
        #pragma unroll
        for (int nt=0;nt<2;++nt){
            int n = R0 + nt*16 + ln;
            float4 res;
            res.x = acc[ot][nt][0] + b4.x;
            res.y = acc[ot][nt][1] + b4.y;
            res.z = acc[ot][nt][2] + b4.z;
            res.w = acc[ot][nt][3] + b4.w;
            *(float4*)(out + (size_t)n*256 + o0) = res;
        }
    }
}

extern "C" void kernel_launch(void* const* d_in, const int* in_sizes, int n_in,
                              void* d_out, int out_size, void* d_ws, size_t ws_size,
                              hipStream_t stream)
{
    (void)in_sizes; (void)n_in; (void)out_size; (void)ws_size;
    const float* nd   = (const float*)d_in[0];
    // d_in[1] = N scalar (compile-time 1024 here)
    const float* bias = (const float*)d_in[2];
    const int* mask   = (const int*)d_in[3];
    const float* Wq = (const float*)d_in[4];
    const float* bq = (const float*)d_in[5];
    const float* Wk = (const float*)d_in[6];
    const float* bk = (const float*)d_in[7];
    const float* Wv = (const float*)d_in[8];
    const float* bv = (const float*)d_in[9];
    const float* Wo = (const float*)d_in[10];
    const float* bo = (const float*)d_in[11];
    float* out = (float*)d_out;

    const size_t ELEMS = (size_t)8*8*1024*32;   // 2M bf16 per buffer
    unsigned short* qb  = (unsigned short*)d_ws;
    unsigned short* kb  = qb  + ELEMS;
    unsigned short* vtb = kb  + ELEMS;
    unsigned short* ab  = vtb + ELEMS;
    unsigned int* bmw   = (unsigned int*)(ab + ELEMS);  // 1MB bitmask
    int* mflag          = (int*)(bmw + 262144);

    detect_mask_k<<<1, 256, 0, stream>>>(mask, mflag);
    mask_prep_k<<<1024, 256, 0, stream>>>((const unsigned int*)mask, mflag, bmw);
    qkv_proj_k<<<384, 256, 0, stream>>>(nd, Wq, bq, Wk, bk, Wv, bv, qb, kb, vtb);
    attn_k<<<512, 512, 0, stream>>>(qb, kb, vtb, bias, bmw, ab);
    oproj_k<<<256, 256, 0, stream>>>(ab, Wo, bo, out);
}